// Round 13
// baseline (104.189 us; speedup 1.0000x reference)
//
#include <hip/hip_runtime.h>

// Problem constants (from reference)
constexpr int L  = 250;   // layers
constexpr int T  = 600;   // traces
constexpr int A  = 30;    // angles

typedef _Float16 h8  __attribute__((ext_vector_type(8)));   // MFMA A/B frag (4 VGPR)
typedef float    f4  __attribute__((ext_vector_type(4)));   // MFMA C/D frag

// refT LDS row stride (halfs): 264 = 256+8 -> 16-B aligned rows, 2-way-free banks
constexpr int RT_LD = 264;

// ---------------- Single fused kernel: TWO blocks per trace ----------------
// Block b = (t, h): computes refT for its 16-angle slice only (halves phase-1
// work per block) and runs phase 2 for its single n-tile. Grid 1200 -> 4.7
// blocks/CU (was 2.34 with 28% CU imbalance at 600) and ~2x resident waves
// for latency hiding of the long Zoeppritz dependency chains.
// NO d_ws use: R8-R11 proved cross-kernel ws handoff is non-deterministic;
// wm is converted f32->f16 in-register (identical rounding to R7/R12).
// Per-element arithmetic identical to R12 -> absmax must stay 0.00390625.
//
// MFMA layouts (verified): A[m=lane&15][k=quad*8+j], B[k=quad*8+j][n=lane&15],
// C/D[row=quad*4+reg][col=lane&15].
__global__ __launch_bounds__(256)
void zoep_fused(const float* __restrict__ vp,
                const float* __restrict__ vs,
                const float* __restrict__ rho,
                const float* __restrict__ theta,
                const float* __restrict__ wm,
                float* __restrict__ out)
{
    __shared__ _Float16 refT[16 * RT_LD];   // 8.25 KB: refT[a_loc][k]
    __shared__ float sth_s[32];
    __shared__ float cth_s[32];

    const int tid = threadIdx.x;
    const int b   = blockIdx.x;      // 0..1199
    const int t   = b >> 1;
    const int h   = b & 1;           // angle half: global a = h*16 + a_loc

    if (tid < 32) {
        const float th = (tid < A) ? theta[tid] : 0.0f;
        sth_s[tid] = sinf(th);
        cth_s[tid] = cosf(th);
    }
    __syncthreads();

    // ---- Phase 1: thread owns interface k = tid (0..255), 16 angles ----
    const int  k     = tid;
    const bool valid = (k < L - 1);
    const int  kc    = valid ? k : (L - 2);   // clamped: loads always in-bounds

    const float a1 = vp[kc * T + t];          // lane-distinct lines, 1 instr/array
    const float a2 = vp[(kc + 1) * T + t];
    const float b1 = vs[kc * T + t];
    const float b2 = vs[(kc + 1) * T + t];
    const float r1 = rho[kc * T + t];
    const float r2 = rho[(kc + 1) * T + t];

    const float ra1  = __builtin_amdgcn_rcpf(a1);
    const float rb1  = r1 * b1, rb2 = r2 * b2;
    const float ra1r = r1 * a1, ra2r = r2 * a2;

#pragma unroll 2
    for (int al = 0; al < 16; ++al) {
        const int   ag  = h * 16 + al;        // global angle 0..31
        const float sth = sth_s[ag];          // LDS broadcast (uniform)
        const float cth = cth_s[ag];

        const float p   = sth * ra1;
        const float s2  = p * a2;             // |.| <= 0.84 < 1 (input ranges)
        const float c2  = sqrtf(1.0f - s2 * s2);
        const float sp1 = p * b1;
        const float cp1 = sqrtf(1.0f - sp1 * sp1);
        const float sp2 = p * b2;
        const float cp2 = sqrtf(1.0f - sp2 * sp2);

        const float k1 = 1.0f - 2.0f * sp1 * sp1;
        const float k2 = 1.0f - 2.0f * sp2 * sp2;
        const float q1 = rb1 * k1;
        const float q2 = rb2 * k2;
        const float P1 = ra1r * k1;
        const float P2 = ra2r * k2;
        const float u1 = 2.0f * rb1 * sp1;
        const float u2 = 2.0f * rb2 * sp2;
        const float S1 = u1 * cp1;
        const float S2 = u2 * cp2;
        const float g1 = u1 * cth;
        const float g2 = u2 * c2;

        // M (row-major)
        const float m00 = -sth, m01 = -cp1, m02 = s2,  m03 = cp2;
        const float m10 =  cth, m11 = -sp1, m12 = c2,  m13 = -sp2;
        const float m20 =  g1,  m21 =  q1,  m22 = g2,  m23 = q2;
        const float m30 = -P1,  m31 =  S1,  m32 = P2,  m33 = -S2;

        // 2x2 minors: s* rows{0,1}, c* rows{2,3}
        const float s3v = m01 * m12 - m11 * m02;
        const float s4v = m01 * m13 - m11 * m03;
        const float s5v = m02 * m13 - m12 * m03;
        const float c3v = m21 * m32 - m31 * m22;
        const float c4v = m21 * m33 - m31 * m23;
        const float c5v = m22 * m33 - m32 * m23;
        const float s0v = m00 * m11 - m10 * m01;
        const float s1v = m00 * m12 - m10 * m02;
        const float s2v = m00 * m13 - m10 * m03;
        const float c0v = m20 * m31 - m30 * m21;
        const float c1v = m20 * m32 - m30 * m22;
        const float c2v = m20 * m33 - m30 * m23;

        const float detM = s0v*c5v - s1v*c4v + s2v*c3v
                         + s3v*c2v - s4v*c1v + s5v*c0v;
        const float A0 = m11*c5v - m12*c4v + m13*c3v;   // minor(0,0)
        const float A3 = m21*s5v - m22*s4v + m23*s3v;   // minor(3,0)

        const float num = m00 * A0 - m30 * A3;
        const float res = 1.0f - 2.0f * num * __builtin_amdgcn_rcpf(detM);

        const bool ok = valid && (ag < A);
        refT[al * RT_LD + k] = (_Float16)(ok ? res : 0.0f);
    }
    __syncthreads();

    // ---- Phase 2: MFMA GEMM, single n-tile (this block's 16 angles) ----
    const int w    = tid >> 6;       // wave 0..3; m-tiles w*4..w*4+3
    const int lane = tid & 63;
    const int quad = lane >> 4;      // 0..3
    const int n16  = lane & 15;      // local angle col

    f4 acc[4];
#pragma unroll
    for (int mi = 0; mi < 4; ++mi) acc[mi] = (f4){0.f, 0.f, 0.f, 0.f};

#pragma unroll
    for (int ks = 0; ks < 8; ++ks) {                 // K = 8 x 32
        const int kofs = ks * 32 + quad * 8;
        const h8 b0 = *(const h8*)&refT[n16 * RT_LD + kofs];
#pragma unroll
        for (int mi = 0; mi < 4; ++mi) {
            const int m    = (w * 4 + mi) * 16 + n16;    // logical wm row 0..255
            const int rowc = (m < L) ? m : (L - 1);      // clamped (store-masked)
            const float* wrow = wm + rowc * L;

            // A-fragment: 8 f32 -> f16, in-bounds via pair clamp + zero-select.
            h8 af;
#pragma unroll
            for (int c = 0; c < 4; ++c) {
                const int col  = kofs + 2 * c;                    // even
                const int colc = (col <= L - 2) ? col : (L - 2);  // pair start <= 248
                const float2 f = *(const float2*)(wrow + colc);   // 8B-aligned
                af[2 * c]     = (_Float16)((col     < L) ? f.x : 0.0f);
                af[2 * c + 1] = (_Float16)((col + 1 < L) ? f.y : 0.0f);
            }

            acc[mi] = __builtin_amdgcn_mfma_f32_16x16x32_f16(af, b0, acc[mi], 0, 0, 0);
        }
    }

    // ---- Epilogue: D[row=quad*4+r][col=n16] -> out[t][l][h*16+n16] ----
    float* outt = out + (size_t)t * (L * A);
    const int a = h * 16 + n16;
#pragma unroll
    for (int mi = 0; mi < 4; ++mi) {
        const int mbase = (w * 4 + mi) * 16 + quad * 4;
        if (a < A) {
#pragma unroll
            for (int r = 0; r < 4; ++r) {
                const int l = mbase + r;
                if (l < L) outt[l * A + a] = acc[mi][r];
            }
        }
    }
}

extern "C" void kernel_launch(void* const* d_in, const int* in_sizes, int n_in,
                              void* d_out, int out_size, void* d_ws, size_t ws_size,
                              hipStream_t stream) {
    (void)in_sizes; (void)n_in; (void)out_size; (void)d_ws; (void)ws_size;
    const float* vp    = (const float*)d_in[0];
    const float* vs    = (const float*)d_in[1];
    const float* rho   = (const float*)d_in[2];
    const float* theta = (const float*)d_in[3];
    const float* wm    = (const float*)d_in[4];
    float* out = (float*)d_out;

    zoep_fused<<<dim3(T * 2), dim3(256), 0, stream>>>(vp, vs, rho, theta, wm, out);
}

// Round 15
// 99.332 us; speedup vs baseline: 1.0489x; 1.0489x over previous
//
#include <hip/hip_runtime.h>

// Problem constants (from reference)
constexpr int L  = 250;   // layers
constexpr int T  = 600;   // traces
constexpr int A  = 30;    // angles

typedef _Float16 h8  __attribute__((ext_vector_type(8)));   // MFMA A/B frag (4 VGPR)
typedef float    f4  __attribute__((ext_vector_type(4)));   // MFMA C/D frag

// refT LDS row stride (halfs): 264 = 256+8 -> 16-B aligned rows, 2-way-free banks
constexpr int RT_LD = 264;

// ---------------- Single fused kernel: one block per trace ----------------
// PROVEN CONFIG (R12: passed, kernel 42 us, absmax 0.00390625). Resubmitted
// verbatim after R13 (angle-split: +40% WRITE_SIZE, regressed) and R14
// (512-thread: intermittent wrong-result mode) both lost.
// NO workspace, NO producer kernel: R8-R11's non-deterministic failures
// implicate cross-kernel d_ws handoff; wm is converted f32->f16 in-register.
//
// Phase 1 (one k per thread): 6 input loads once into registers — one load
//   instr per array per wave puts 64 distinct lines in flight. Uniform
//   control flow: clamped load index, validity masked at the refT write.
// Phase 2: out[t] = wm @ ref via v_mfma_f32_16x16x32_f16.
//   Verified layouts: A[m=lane&15][k=quad*8+j], B[k=quad*8+j][n=lane&15],
//   C/D[row=quad*4+reg][col=lane&15].
__global__ __launch_bounds__(256)
void zoep_fused(const float* __restrict__ vp,
                const float* __restrict__ vs,
                const float* __restrict__ rho,
                const float* __restrict__ theta,
                const float* __restrict__ wm,
                float* __restrict__ out)
{
    __shared__ _Float16 refT[32 * RT_LD];   // 16.5 KB: refT[a][k]
    __shared__ float sth_s[32];
    __shared__ float cth_s[32];

    const int tid = threadIdx.x;
    const int t   = blockIdx.x;

    if (tid < 32) {
        const float th = (tid < A) ? theta[tid] : 0.0f;
        sth_s[tid] = sinf(th);
        cth_s[tid] = cosf(th);
    }
    __syncthreads();

    // ---- Phase 1: thread owns interface k = tid (0..255) ----
    const int  k     = tid;
    const bool valid = (k < L - 1);
    const int  kc    = valid ? k : (L - 2);   // clamped: loads always in-bounds

    const float a1 = vp[kc * T + t];          // lane-distinct lines, 1 instr/array
    const float a2 = vp[(kc + 1) * T + t];
    const float b1 = vs[kc * T + t];
    const float b2 = vs[(kc + 1) * T + t];
    const float r1 = rho[kc * T + t];
    const float r2 = rho[(kc + 1) * T + t];

    const float ra1  = __builtin_amdgcn_rcpf(a1);
    const float rb1  = r1 * b1, rb2 = r2 * b2;
    const float ra1r = r1 * a1, ra2r = r2 * a2;

#pragma unroll 2
    for (int a = 0; a < A; ++a) {
        const float sth = sth_s[a];           // LDS broadcast (uniform a)
        const float cth = cth_s[a];

        const float p   = sth * ra1;
        const float s2  = p * a2;             // |.| <= 0.84 < 1 (input ranges)
        const float c2  = sqrtf(1.0f - s2 * s2);
        const float sp1 = p * b1;
        const float cp1 = sqrtf(1.0f - sp1 * sp1);
        const float sp2 = p * b2;
        const float cp2 = sqrtf(1.0f - sp2 * sp2);

        const float k1 = 1.0f - 2.0f * sp1 * sp1;
        const float k2 = 1.0f - 2.0f * sp2 * sp2;
        const float q1 = rb1 * k1;
        const float q2 = rb2 * k2;
        const float P1 = ra1r * k1;
        const float P2 = ra2r * k2;
        const float u1 = 2.0f * rb1 * sp1;
        const float u2 = 2.0f * rb2 * sp2;
        const float S1 = u1 * cp1;
        const float S2 = u2 * cp2;
        const float g1 = u1 * cth;
        const float g2 = u2 * c2;

        // M (row-major)
        const float m00 = -sth, m01 = -cp1, m02 = s2,  m03 = cp2;
        const float m10 =  cth, m11 = -sp1, m12 = c2,  m13 = -sp2;
        const float m20 =  g1,  m21 =  q1,  m22 = g2,  m23 = q2;
        const float m30 = -P1,  m31 =  S1,  m32 = P2,  m33 = -S2;

        // 2x2 minors: s* rows{0,1}, c* rows{2,3}
        const float s3v = m01 * m12 - m11 * m02;
        const float s4v = m01 * m13 - m11 * m03;
        const float s5v = m02 * m13 - m12 * m03;
        const float c3v = m21 * m32 - m31 * m22;
        const float c4v = m21 * m33 - m31 * m23;
        const float c5v = m22 * m33 - m32 * m23;
        const float s0v = m00 * m11 - m10 * m01;
        const float s1v = m00 * m12 - m10 * m02;
        const float s2v = m00 * m13 - m10 * m03;
        const float c0v = m20 * m31 - m30 * m21;
        const float c1v = m20 * m32 - m30 * m22;
        const float c2v = m20 * m33 - m30 * m23;

        const float detM = s0v*c5v - s1v*c4v + s2v*c3v
                         + s3v*c2v - s4v*c1v + s5v*c0v;
        const float A0 = m11*c5v - m12*c4v + m13*c3v;   // minor(0,0)
        const float A3 = m21*s5v - m22*s4v + m23*s3v;   // minor(3,0)

        const float num = m00 * A0 - m30 * A3;
        const float res = 1.0f - 2.0f * num * __builtin_amdgcn_rcpf(detM);

        refT[a * RT_LD + k] = (_Float16)(valid ? res : 0.0f);
    }
    // zero pad rows a = 30, 31 (column k)
    refT[30 * RT_LD + k] = (_Float16)0.0f;
    refT[31 * RT_LD + k] = (_Float16)0.0f;
    __syncthreads();

    // ---- Phase 2: MFMA GEMM. wave w owns m-tiles w*4..w*4+3, both n-tiles.
    const int w    = tid >> 6;       // wave 0..3
    const int lane = tid & 63;
    const int quad = lane >> 4;      // 0..3
    const int n16  = lane & 15;

    f4 acc[4][2];
#pragma unroll
    for (int mi = 0; mi < 4; ++mi)
#pragma unroll
        for (int nt = 0; nt < 2; ++nt) acc[mi][nt] = (f4){0.f, 0.f, 0.f, 0.f};

#pragma unroll
    for (int ks = 0; ks < 8; ++ks) {                 // K = 8 x 32
        const int kofs = ks * 32 + quad * 8;
        const h8 b0 = *(const h8*)&refT[ n16       * RT_LD + kofs];
        const h8 b1 = *(const h8*)&refT[(16 + n16) * RT_LD + kofs];
#pragma unroll
        for (int mi = 0; mi < 4; ++mi) {
            const int m    = (w * 4 + mi) * 16 + n16;    // logical wm row 0..255
            const int rowc = (m < L) ? m : (L - 1);      // clamped (store-masked)
            const float* wrow = wm + rowc * L;

            // A-fragment: 8 f32 -> f16, in-bounds via pair clamp + zero-select.
            // Cols >= 250 multiply zero refT columns; zero-select keeps them
            // finite AND all loads inside wm[0..62499].
            h8 af;
#pragma unroll
            for (int c = 0; c < 4; ++c) {
                const int col  = kofs + 2 * c;                    // even
                const int colc = (col <= L - 2) ? col : (L - 2);  // pair start <= 248
                const float2 f = *(const float2*)(wrow + colc);   // 8B-aligned
                af[2 * c]     = (_Float16)((col     < L) ? f.x : 0.0f);
                af[2 * c + 1] = (_Float16)((col + 1 < L) ? f.y : 0.0f);
            }

            acc[mi][0] = __builtin_amdgcn_mfma_f32_16x16x32_f16(af, b0, acc[mi][0], 0, 0, 0);
            acc[mi][1] = __builtin_amdgcn_mfma_f32_16x16x32_f16(af, b1, acc[mi][1], 0, 0, 0);
        }
    }

    // ---- Epilogue: D[row=quad*4+r][col=n16] -> out[t][l][a] ----
    float* outt = out + (size_t)t * (L * A);
#pragma unroll
    for (int mi = 0; mi < 4; ++mi) {
        const int mbase = (w * 4 + mi) * 16 + quad * 4;
#pragma unroll
        for (int nt = 0; nt < 2; ++nt) {
            const int a = nt * 16 + n16;
            if (a < A) {
#pragma unroll
                for (int r = 0; r < 4; ++r) {
                    const int l = mbase + r;
                    if (l < L) outt[l * A + a] = acc[mi][nt][r];
                }
            }
        }
    }
}

extern "C" void kernel_launch(void* const* d_in, const int* in_sizes, int n_in,
                              void* d_out, int out_size, void* d_ws, size_t ws_size,
                              hipStream_t stream) {
    (void)in_sizes; (void)n_in; (void)out_size; (void)d_ws; (void)ws_size;
    const float* vp    = (const float*)d_in[0];
    const float* vs    = (const float*)d_in[1];
    const float* rho   = (const float*)d_in[2];
    const float* theta = (const float*)d_in[3];
    const float* wm    = (const float*)d_in[4];
    float* out = (float*)d_out;

    zoep_fused<<<dim3(T), dim3(256), 0, stream>>>(vp, vs, rho, theta, wm, out);
}